// Round 8
// baseline (224.779 us; speedup 1.0000x reference)
//
#include <hip/hip_runtime.h>
#include <stdint.h>

#define BATCH 16
#define HW (1024*1024)                 // pixels per batch image
#define NPIX (BATCH * HW)              // 16,777,216 total pixels
#define NV4 (NPIX / 4)                 // 4,194,304 float4 elements
#define SBLK 64                        // scan blocks per batch
#define SGRID (SBLK * BATCH)           // 1024 scan blocks
#define SV4 4096                       // vf4 per scan block (16/thread)
#define OVPT 2                         // vf4 per thread in out kernel
#define OGRID (NV4 / 256 / OVPT)       // 8192 out blocks

typedef float vf4 __attribute__((ext_vector_type(4)));

// ---------------------------------------------------------------------------
// Kernel 1: full-scan streaming reduction (R0/R1/R6 proven structure).
//   minb  = min occupied histogram bin (0x7FFF if none in-range)
//   maxb  = max occupied histogram bin (-1 if none)
//   valid = any pixel with integral mi in [0,255]
// flag = valid && (minb != maxb): for a valid pixel mi=n its bin index
// equals n, and all |i-k|*hist[k] terms are non-negative integers (no fp
// cancellation in the reference matvec), so mask.max()>0 iff a second bin
// is occupied.  (Harness-verified absmax=0 in rounds 0/1/3/4/5/6.)
//
// Cached loads: this pure-read phase pays the input's one mandatory HBM
// crossing at full read BW and leaves it LLC-resident for out_kernel
// (cold-read-into-write-phase measured ~30 µs slower, R4/R5).
// ---------------------------------------------------------------------------
__global__ __launch_bounds__(256) void scan_kernel(const float* __restrict__ in,
                                                   uint2* __restrict__ partials) {
    const int tid = threadIdx.x;
    const int blk = blockIdx.x;
    int minb = 0x7FFF, maxb = -1, valid = 0;

    const vf4* src = (const vf4*)in + (size_t)blk * SV4;
    for (int i = tid; i < SV4; i += 256) {
        vf4 x = src[i];                               // cached: warm the LLC for kernel 2
        float v[4] = {x.x, x.y, x.z, x.w};
#pragma unroll
        for (int k = 0; k < 4; ++k) {
            float mi = v[k] * 255.0f;                 // replicate reference arithmetic
            if (mi >= 0.0f && mi <= 255.0f) {         // histogram range, edges inclusive
                int b = (int)(mi * (256.0f / 255.0f));
                if (b > 255) b = 255;                 // right edge -> last bin
                minb = min(minb, b);
                maxb = max(maxb, b);
                valid |= (mi == rintf(mi)) ? 1 : 0;   // round-half-even == jnp.round
            }
        }
    }
    // 64-lane butterfly reduce within each wave
#pragma unroll
    for (int off = 32; off > 0; off >>= 1) {
        minb  = min(minb, __shfl_xor(minb, off));
        maxb  = max(maxb, __shfl_xor(maxb, off));
        valid |= __shfl_xor(valid, off);
    }
    // cross-wave reduce via LDS (4 waves)
    __shared__ int sm[4], sx[4], sv[4];
    const int w = tid >> 6;
    if ((tid & 63) == 0) { sm[w] = minb; sx[w] = maxb; sv[w] = valid; }
    __syncthreads();
    if (tid == 0) {
#pragma unroll
        for (int i = 1; i < 4; ++i) {
            minb  = min(minb, sm[i]);
            maxb  = max(maxb, sx[i]);
            valid |= sv[i];
        }
        uint2 p;
        p.x = ((unsigned)(minb & 0xFFFF) << 16) | (unsigned)(maxb & 0xFFFF);
        p.y = (unsigned)valid;
        partials[blk] = p;
    }
}

// ---------------------------------------------------------------------------
// Kernel 2: fused flag-reduce + mask-apply + 2-way softmax, 2 vf4/thread.
// A/B vs R6: PLAIN cached stores instead of nontemporal. Rationale: the
// harness's fillBufferAligned sustains 6.7-6.8 TB/s with plain stores
// (L2 write-combining into full lines), while our NT-store write phase
// implies only ~3.4 TB/s effective. 128 MB of write-allocate traffic plus
// the 64 MB input fits the 256 MB LLC, so input eviction risk is bounded.
// m = flag ? (x*255)/255 : 0 ; o0 = 1/(1+e^{1-2m}) ; o1 = e * o0.
// Output layout: [msks0 (16M floats) | msks1 (16M floats)].
// ---------------------------------------------------------------------------
__device__ __forceinline__ float2 softmax2(float x, float fm) {
    float mi = x * 255.0f;
    float m = (mi / 255.0f) * fm;      // fm in {0,1}: masked or zeroed
    float e = expf(1.0f - 2.0f * m);   // e^{b-a}, b-a = (1-m)-m
    float r = 1.0f / (1.0f + e);
    return make_float2(r, e * r);      // (e^a, e^b) / (e^a+e^b)
}

__global__ __launch_bounds__(256) void out_kernel(const float* __restrict__ in,
                                                  const uint2* __restrict__ partials,
                                                  float* __restrict__ out) {
    const int batch = blockIdx.x >> 9;             // 512 out-blocks per batch image
    const size_t base = (size_t)blockIdx.x * (256 * OVPT) + threadIdx.x;

    // issue both (LLC-resident) input loads first — latency overlaps the reduce
    const vf4* src = (const vf4*)in;
    vf4 x0 = src[base];
    vf4 x1 = src[base + 256];

    __shared__ float s_fm;
    if (threadIdx.x < 64) {
        uint2 p = partials[batch * SBLK + threadIdx.x];
        int mn = (int)(short)(p.x >> 16);          // sign-extend: 0x7FFF stays, -1 stays
        int mx = (int)(short)(p.x & 0xFFFF);
        unsigned vv = p.y;
#pragma unroll
        for (int off = 32; off > 0; off >>= 1) {
            mn = min(mn, __shfl_xor(mn, off));
            mx = max(mx, __shfl_xor(mx, off));
            vv |= (unsigned)__shfl_xor((int)vv, off);
        }
        if (threadIdx.x == 0) s_fm = (vv && mn != mx) ? 1.0f : 0.0f;
    }
    __syncthreads();
    const float fm = s_fm;

    vf4* o0p = (vf4*)out;
    vf4* o1p = (vf4*)(out + (size_t)NPIX);
#pragma unroll
    for (int j = 0; j < OVPT; ++j) {
        vf4 x = (j == 0) ? x0 : x1;
        float2 rx = softmax2(x.x, fm);
        float2 ry = softmax2(x.y, fm);
        float2 rz = softmax2(x.z, fm);
        float2 rw = softmax2(x.w, fm);
        vf4 o0 = {rx.x, ry.x, rz.x, rw.x};
        vf4 o1 = {rx.y, ry.y, rz.y, rw.y};
        const size_t idx = base + (size_t)j * 256;
        o0p[idx] = o0;                              // plain stores: L2 write-combining
        o1p[idx] = o1;
    }
}

// ---------------------------------------------------------------------------
extern "C" void kernel_launch(void* const* d_in, const int* in_sizes, int n_in,
                              void* d_out, int out_size, void* d_ws, size_t ws_size,
                              hipStream_t stream) {
    const float* irr = (const float*)d_in[0];
    // d_in[1] (image_vis) is unused by the reference's outputs.
    float* out = (float*)d_out;

    uint2* partials = (uint2*)d_ws;                      // 1024 uint2 = 8 KB
    // No memset needed: partials fully written by scan_kernel before any read.

    scan_kernel<<<SGRID, 256, 0, stream>>>(irr, partials);
    out_kernel<<<OGRID, 256, 0, stream>>>(irr, partials, out);
}